// Round 7
// baseline (50.212 us; speedup 1.0000x reference)
//
#include <hip/hip_runtime.h>
#include <math.h>

#define NB 1024
#define NC 64
#define NH 64
#define ND 256
#define NHID 256

typedef float f4 __attribute__((ext_vector_type(4)));

// ws layout (floats): [0..255] = v_h, [256] = mask mode (int),
// [1024 .. 1024+64*256)     = P1 partials  (needs ws >=    69,632 B)
// [32768 .. 32768+65536)    = raw scores   (needs ws >=   393,216 B)
#define WS_PART_OFF 1024
#define WS_S_OFF    32768

// mask storage modes: 0 = int32, 1 = byte (bool), 2 = float32
__device__ __forceinline__ bool read_mask(const void* m, int idx, int mode) {
  if (mode == 2) return ((const float*)m)[idx] != 0.0f;
  if (mode == 1) return ((const unsigned char*)m)[idx] != 0;
  return ((const int*)m)[idx] != 0;
}

__device__ __forceinline__ void detect_mode(const unsigned int* mask_cand,
                                            const unsigned int* mask_hist,
                                            int* dst) {
  int sawf = 0; unsigned int big = 0;
  for (int i = 0; i < 32; ++i) {
    unsigned int a = mask_hist[i], b = mask_cand[i];
    if (a == 0x3f800000u || b == 0x3f800000u) sawf = 1;
    if ((a > 1u && a != 0x3f800000u) || (b > 1u && b != 0x3f800000u)) big = 1;
  }
  *dst = sawf ? 2 : (big ? 1 : 0);
}

__device__ __forceinline__ float dot4(f4 a, f4 b) {
  return fmaf(a.x, b.x, fmaf(a.y, b.y, fmaf(a.z, b.z, a.w * b.w)));
}

#define BFLY(p) { p += __shfl_xor(p, 32); p += __shfl_xor(p, 16); p += __shfl_xor(p, 8); \
                  p += __shfl_xor(p, 4);  p += __shfl_xor(p, 2);  p += __shfl_xor(p, 1); }

// ---- P1: 64 blocks x 256 threads: partial v_h over 4 j-rows each ----
__global__ __launch_bounds__(256) void precompute_p1(
    const float* __restrict__ W1, const float* __restrict__ W2,
    float* __restrict__ ws)
{
  const int g = blockIdx.x;
  const int d = threadIdx.x;
  float acc = 0.f;
  #pragma unroll
  for (int jj = 0; jj < 4; ++jj) {
    int j = g * 4 + jj;
    acc = fmaf(W1[(size_t)j * (2 * ND) + ND + d], W2[j], acc);
  }
  ws[WS_PART_OFF + g * ND + d] = acc;
}

// ---- P2: 1 block x 256 threads: reduce partials, detect mask mode ----
__global__ __launch_bounds__(256) void precompute_p2(
    const unsigned int* __restrict__ mask_cand,
    const unsigned int* __restrict__ mask_hist,
    float* __restrict__ ws)
{
  const int d = threadIdx.x;
  float acc = 0.f;
  #pragma unroll 8
  for (int g = 0; g < 64; ++g) acc += ws[WS_PART_OFF + g * ND + d];
  ws[d] = acc;
  if (d == 0) detect_mode(mask_cand, mask_hist, (int*)ws + ND);
}

// ---- fallback single-block precompute (small ws) ----
__global__ __launch_bounds__(1024) void precompute_fallback(
    const float* __restrict__ W1, const float* __restrict__ W2,
    const unsigned int* __restrict__ mask_cand,
    const unsigned int* __restrict__ mask_hist,
    float* __restrict__ ws)
{
  __shared__ float w2_lds[NHID];
  __shared__ float partial[4][ND];
  int t = threadIdx.x;
  if (t < NHID) w2_lds[t] = W2[t];
  __syncthreads();
  int d = t & (ND - 1);
  int g = t >> 8;
  float acc = 0.f;
  #pragma unroll 8
  for (int j = g * 64; j < g * 64 + 64; ++j)
    acc = fmaf(W1[(size_t)j * (2 * ND) + ND + d], w2_lds[j], acc);
  partial[g][d] = acc;
  __syncthreads();
  if (t < ND)
    ws[t] = partial[0][t] + partial[1][t] + partial[2][t] + partial[3][t];
  if (t == 0) detect_mode(mask_cand, mask_hist, (int*)ws + ND);
}

// ---- A: raw scores, pure linear read stream (67 MB), no LDS, no barriers.
// Wave W owns rows W*8..W*8+7 (8 KB contiguous); every load instruction is
// 64 lanes x 16 B = 1 KB contiguous (the m13-copy pattern). ----
__global__ __launch_bounds__(256) void score_stream_kernel(
    const float* __restrict__ hist,
    const float* __restrict__ ws,
    float* __restrict__ s_out)
{
  const int t = threadIdx.x, lane = t & 63;
  const int W = blockIdx.x * 4 + (t >> 6);            // global wave id, 0..8191
  const f4* h4 = reinterpret_cast<const f4*>(hist) + (size_t)W * 512;
  const f4 vh = reinterpret_cast<const f4*>(ws)[lane]; // 1 KB, L1-hot

  f4 x0 = h4[0 * 64 + lane], x1 = h4[1 * 64 + lane];
  f4 x2 = h4[2 * 64 + lane], x3 = h4[3 * 64 + lane];
  f4 x4 = h4[4 * 64 + lane], x5 = h4[5 * 64 + lane];
  f4 x6 = h4[6 * 64 + lane], x7 = h4[7 * 64 + lane];

  float p0 = dot4(x0, vh), p1 = dot4(x1, vh), p2 = dot4(x2, vh), p3 = dot4(x3, vh);
  float p4 = dot4(x4, vh), p5 = dot4(x5, vh), p6 = dot4(x6, vh), p7 = dot4(x7, vh);
  BFLY(p0) BFLY(p1) BFLY(p2) BFLY(p3) BFLY(p4) BFLY(p5) BFLY(p6) BFLY(p7)

  float v = p0;
  if (lane == 1) v = p1;  if (lane == 2) v = p2;  if (lane == 3) v = p3;
  if (lane == 4) v = p4;  if (lane == 5) v = p5;  if (lane == 6) v = p6;
  if (lane == 7) v = p7;
  if (lane < 8) s_out[W * 8 + lane] = v;
}

// ---- B: softmax + uv + masked broadcast, one block per b.
// hist loads (L3-resident after A) are hoisted before the barrier; stores are
// the fill-kernel pattern: block-linear, 1 KB contiguous per wave instr. ----
__global__ __launch_bounds__(256) void uv_bcast_kernel(
    const float* __restrict__ hist,
    const void* __restrict__ mask_cand_v,
    const void* __restrict__ mask_hist_v,
    const float* __restrict__ ws,
    const float* __restrict__ s_in,
    float* __restrict__ out)
{
  const int b = blockIdx.x, t = threadIdx.x, lane = t & 63, w = t >> 6;
  __shared__ float w_lds[NH];
  __shared__ f4 red[4][64];                    // 4 KB

  const int mode = ((const int*)ws)[ND];
  const f4* hb4 = reinterpret_cast<const f4*>(hist) + (size_t)b * 4096;

  // hoisted loads: thread t holds rows k*4+w, f4-col lane (linear: t + k*256)
  f4 xr[16];
  #pragma unroll
  for (int k = 0; k < 16; ++k) xr[k] = hb4[k * 256 + t];

  // wave 0: masked softmax over H=64
  if (t < 64) {
    float s = read_mask(mask_hist_v, b * NH + t, mode) ? s_in[b * NH + t] : -3.0e38f;
    float m = s;
    m = fmaxf(m, __shfl_xor(m, 32)); m = fmaxf(m, __shfl_xor(m, 16));
    m = fmaxf(m, __shfl_xor(m, 8));  m = fmaxf(m, __shfl_xor(m, 4));
    m = fmaxf(m, __shfl_xor(m, 2));  m = fmaxf(m, __shfl_xor(m, 1));
    float e = expf(s - m);
    float sum = e;
    BFLY(sum)
    w_lds[t] = e / sum;
  }
  __syncthreads();

  f4 acc = {0.f, 0.f, 0.f, 0.f};
  #pragma unroll
  for (int k = 0; k < 16; ++k) acc += w_lds[k * 4 + w] * xr[k];
  red[w][lane] = acc;
  __syncthreads();

  f4 uv = red[0][lane] + red[1][lane] + red[2][lane] + red[3][lane];
  f4* ob4 = reinterpret_cast<f4*>(out) + (size_t)b * 4096;
  const f4 zero = {0.f, 0.f, 0.f, 0.f};
  #pragma unroll
  for (int k = 0; k < 16; ++k) {
    int c = k * 4 + w;                          // wave-uniform row
    bool mc = read_mask(mask_cand_v, b * NC + c, mode);
    f4 val = mc ? uv : zero;
    __builtin_nontemporal_store(val, &ob4[k * 256 + t]);   // linear per block
  }
}

// ---- fallback fused kernel (small ws): R3 design, known-good ----
__global__ __launch_bounds__(512, 8) void fused_fallback_kernel(
    const float* __restrict__ hist,
    const void* __restrict__ mask_cand_v,
    const void* __restrict__ mask_hist_v,
    const float* __restrict__ ws,
    float* __restrict__ out)
{
  const int b = blockIdx.x;
  const int t = threadIdx.x;
  const int lane = t & 63;
  const int w = t >> 6;

  __shared__ float s_lds[NH];
  __shared__ f4 part[8][64];

  const int mode = ((const int*)ws)[ND];
  const f4* hb4 = reinterpret_cast<const f4*>(hist) + (size_t)b * 4096;
  const f4* vh4p = reinterpret_cast<const f4*>(ws);

  {
    const int r = t >> 3, cg = t & 7;
    float p = 0.f;
    #pragma unroll
    for (int i = 0; i < 8; ++i) {
      f4 x = hb4[r * 64 + i * 8 + cg];
      f4 v = vh4p[i * 8 + cg];
      p = fmaf(x.x, v.x, fmaf(x.y, v.y, fmaf(x.z, v.z, fmaf(x.w, v.w, p))));
    }
    p += __shfl_xor(p, 1); p += __shfl_xor(p, 2); p += __shfl_xor(p, 4);
    if (cg == 0)
      s_lds[r] = read_mask(mask_hist_v, b * NH + r, mode) ? p : -3.0e38f;
  }
  __syncthreads();

  float wval;
  {
    float s = s_lds[lane];
    float m = s;
    #pragma unroll
    for (int off = 32; off; off >>= 1) m = fmaxf(m, __shfl_xor(m, off));
    float e = expf(s - m);
    float sum = e;
    #pragma unroll
    for (int off = 32; off; off >>= 1) sum += __shfl_xor(sum, off);
    wval = e / sum;
  }

  {
    f4 acc = {0.f, 0.f, 0.f, 0.f};
    #pragma unroll
    for (int j = 0; j < 8; ++j) {
      float wj = __shfl(wval, w * 8 + j);
      f4 x = hb4[(w * 8 + j) * 64 + lane];
      acc += wj * x;
    }
    part[w][lane] = acc;
  }
  __syncthreads();

  {
    f4 uv = part[0][lane];
    #pragma unroll
    for (int g = 1; g < 8; ++g) uv += part[g][lane];
    f4* ob4 = reinterpret_cast<f4*>(out) + (size_t)b * 4096;
    const f4 zero = {0.f, 0.f, 0.f, 0.f};
    #pragma unroll
    for (int k = 0; k < 8; ++k) {
      int c = w + k * 8;
      bool mc = read_mask(mask_cand_v, b * NC + c, mode);
      f4 val = mc ? uv : zero;
      __builtin_nontemporal_store(val, &ob4[c * 64 + lane]);
    }
  }
}

extern "C" void kernel_launch(void* const* d_in, const int* in_sizes, int n_in,
                              void* d_out, int out_size, void* d_ws, size_t ws_size,
                              hipStream_t stream) {
  (void)in_sizes; (void)n_in; (void)out_size;
  // inputs: 0 cand [B,C,D] (UNUSED — softmax shift-invariance kills the
  // candidate term), 1 hist [B,H,D], 2 mask_cand, 3 mask_hist,
  // 4 W1 [HID,2D], 5 b1 (unused), 6 W2 [1,HID], 7 b2 (unused)
  const float* hist = (const float*)d_in[1];
  const void*  mask_cand = d_in[2];
  const void*  mask_hist = d_in[3];
  const float* W1 = (const float*)d_in[4];
  const float* W2 = (const float*)d_in[6];
  float* ws = (float*)d_ws;
  float* out = (float*)d_out;

  const bool mid = ws_size >= (size_t)(WS_PART_OFF + 64 * ND) * sizeof(float);
  const bool big = ws_size >= (size_t)(WS_S_OFF + NB * NH) * sizeof(float);

  if (mid) {
    precompute_p1<<<64, 256, 0, stream>>>(W1, W2, ws);
    precompute_p2<<<1, 256, 0, stream>>>(
        (const unsigned int*)mask_cand, (const unsigned int*)mask_hist, ws);
  } else {
    precompute_fallback<<<1, 1024, 0, stream>>>(
        W1, W2, (const unsigned int*)mask_cand, (const unsigned int*)mask_hist, ws);
  }

  if (big) {
    score_stream_kernel<<<2048, 256, 0, stream>>>(hist, ws, ws + WS_S_OFF);
    uv_bcast_kernel<<<NB, 256, 0, stream>>>(hist, mask_cand, mask_hist, ws,
                                            ws + WS_S_OFF, out);
  } else {
    fused_fallback_kernel<<<NB, 512, 0, stream>>>(hist, mask_cand, mask_hist, ws, out);
  }
}

// Round 8
// 43.458 us; speedup vs baseline: 1.1554x; 1.1554x over previous
//
#include <hip/hip_runtime.h>
#include <math.h>

#define NB 1024
#define NC 64
#define NH 64
#define ND 256
#define NHID 256

typedef float f4 __attribute__((ext_vector_type(4)));

// ws layout (floats): [0..255] = v_h, [256] = mask mode (int),
// [1024 .. 1024+64*256) = P1 partials (needs ws >= 69,632 B)
#define WS_PART_OFF 1024

// mask storage modes: 0 = int32, 1 = byte (bool), 2 = float32
__device__ __forceinline__ bool read_mask(const void* m, int idx, int mode) {
  if (mode == 2) return ((const float*)m)[idx] != 0.0f;
  if (mode == 1) return ((const unsigned char*)m)[idx] != 0;
  return ((const int*)m)[idx] != 0;
}

__device__ __forceinline__ void detect_mode(const unsigned int* mask_cand,
                                            const unsigned int* mask_hist,
                                            int* dst) {
  int sawf = 0; unsigned int big = 0;
  for (int i = 0; i < 32; ++i) {
    unsigned int a = mask_hist[i], b = mask_cand[i];
    if (a == 0x3f800000u || b == 0x3f800000u) sawf = 1;
    if ((a > 1u && a != 0x3f800000u) || (b > 1u && b != 0x3f800000u)) big = 1;
  }
  *dst = sawf ? 2 : (big ? 1 : 0);
}

__device__ __forceinline__ float dot4(f4 a, f4 b) {
  return fmaf(a.x, b.x, fmaf(a.y, b.y, fmaf(a.z, b.z, a.w * b.w)));
}

#define BFLY(p) { p += __shfl_xor(p, 32); p += __shfl_xor(p, 16); p += __shfl_xor(p, 8); \
                  p += __shfl_xor(p, 4);  p += __shfl_xor(p, 2);  p += __shfl_xor(p, 1); }

// ---- P1: 64 blocks x 256 threads: partial v_h over 4 j-rows each ----
__global__ __launch_bounds__(256) void precompute_p1(
    const float* __restrict__ W1, const float* __restrict__ W2,
    float* __restrict__ ws)
{
  const int g = blockIdx.x;
  const int d = threadIdx.x;
  float acc = 0.f;
  #pragma unroll
  for (int jj = 0; jj < 4; ++jj) {
    int j = g * 4 + jj;
    acc = fmaf(W1[(size_t)j * (2 * ND) + ND + d], W2[j], acc);
  }
  ws[WS_PART_OFF + g * ND + d] = acc;
}

// ---- P2: 1 block x 256 threads: reduce partials, detect mask mode ----
__global__ __launch_bounds__(256) void precompute_p2(
    const unsigned int* __restrict__ mask_cand,
    const unsigned int* __restrict__ mask_hist,
    float* __restrict__ ws)
{
  const int d = threadIdx.x;
  float acc = 0.f;
  #pragma unroll 8
  for (int g = 0; g < 64; ++g) acc += ws[WS_PART_OFF + g * ND + d];
  ws[d] = acc;
  if (d == 0) detect_mode(mask_cand, mask_hist, (int*)ws + ND);
}

// ---- fallback single-block precompute (small ws) ----
__global__ __launch_bounds__(1024) void precompute_fallback(
    const float* __restrict__ W1, const float* __restrict__ W2,
    const unsigned int* __restrict__ mask_cand,
    const unsigned int* __restrict__ mask_hist,
    float* __restrict__ ws)
{
  __shared__ float w2_lds[NHID];
  __shared__ float partial[4][ND];
  int t = threadIdx.x;
  if (t < NHID) w2_lds[t] = W2[t];
  __syncthreads();
  int d = t & (ND - 1);
  int g = t >> 8;
  float acc = 0.f;
  #pragma unroll 8
  for (int j = g * 64; j < g * 64 + 64; ++j)
    acc = fmaf(W1[(size_t)j * (2 * ND) + ND + d], w2_lds[j], acc);
  partial[g][d] = acc;
  __syncthreads();
  if (t < ND)
    ws[t] = partial[0][t] + partial[1][t] + partial[2][t] + partial[3][t];
  if (t == 0) detect_mode(mask_cand, mask_hist, (int*)ws + ND);
}

// ---- main fused kernel: one block (512 thr = 8 waves) per batch b.
// Wave w owns rows w*8..w*8+7, held ENTIRELY in registers (8 f4/thread);
// every global load/store instruction is 64 lanes x 16 B = 1 KB contiguous.
// No global re-read; plain stores so L3 can absorb the write stream. ----
__global__ __launch_bounds__(512, 8) void fused_kernel(
    const float* __restrict__ hist,
    const void* __restrict__ mask_cand_v,
    const void* __restrict__ mask_hist_v,
    const float* __restrict__ ws,
    float* __restrict__ out)
{
  const int b = blockIdx.x, t = threadIdx.x, lane = t & 63, w = t >> 6;
  __shared__ float s_lds[NH];
  __shared__ f4 red[8][64];                      // 8 KB

  const int mode = ((const int*)ws)[ND];
  const f4* hb4 = reinterpret_cast<const f4*>(hist) + (size_t)b * 4096;
  const f4 vh = reinterpret_cast<const f4*>(ws)[lane];   // 1 KB, L1-hot

  // hoist wave-uniform mask_cand bits for this wave's 8 output rows
  bool mc[8];
  #pragma unroll
  for (int j = 0; j < 8; ++j)
    mc[j] = read_mask(mask_cand_v, b * NC + w * 8 + j, mode);

  // ---- phase 1: load 8 rows into registers, dot with v_h, reduce ----
  f4 x0 = hb4[(w * 8 + 0) * 64 + lane], x1 = hb4[(w * 8 + 1) * 64 + lane];
  f4 x2 = hb4[(w * 8 + 2) * 64 + lane], x3 = hb4[(w * 8 + 3) * 64 + lane];
  f4 x4 = hb4[(w * 8 + 4) * 64 + lane], x5 = hb4[(w * 8 + 5) * 64 + lane];
  f4 x6 = hb4[(w * 8 + 6) * 64 + lane], x7 = hb4[(w * 8 + 7) * 64 + lane];

  float p0 = dot4(x0, vh), p1 = dot4(x1, vh), p2 = dot4(x2, vh), p3 = dot4(x3, vh);
  float p4 = dot4(x4, vh), p5 = dot4(x5, vh), p6 = dot4(x6, vh), p7 = dot4(x7, vh);
  BFLY(p0) BFLY(p1) BFLY(p2) BFLY(p3) BFLY(p4) BFLY(p5) BFLY(p6) BFLY(p7)

  if (lane < 8) {
    float v = p0;
    if (lane == 1) v = p1;  if (lane == 2) v = p2;  if (lane == 3) v = p3;
    if (lane == 4) v = p4;  if (lane == 5) v = p5;  if (lane == 6) v = p6;
    if (lane == 7) v = p7;
    int h = w * 8 + lane;
    s_lds[h] = read_mask(mask_hist_v, b * NH + h, mode) ? v : -3.0e38f;
  }
  __syncthreads();

  // ---- phase 2: softmax over H=64, redundant per wave (no extra barrier) ----
  float wval;
  {
    float s = s_lds[lane];
    float m = s;
    m = fmaxf(m, __shfl_xor(m, 32)); m = fmaxf(m, __shfl_xor(m, 16));
    m = fmaxf(m, __shfl_xor(m, 8));  m = fmaxf(m, __shfl_xor(m, 4));
    m = fmaxf(m, __shfl_xor(m, 2));  m = fmaxf(m, __shfl_xor(m, 1));
    float e = expf(s - m);
    float sum = e;
    BFLY(sum)
    wval = e / sum;                  // weight for h = lane
  }

  // ---- phase 3: weighted sum from REGISTERS (no global re-read) ----
  {
    f4 acc = __shfl(wval, w * 8 + 0) * x0;
    acc += __shfl(wval, w * 8 + 1) * x1;
    acc += __shfl(wval, w * 8 + 2) * x2;
    acc += __shfl(wval, w * 8 + 3) * x3;
    acc += __shfl(wval, w * 8 + 4) * x4;
    acc += __shfl(wval, w * 8 + 5) * x5;
    acc += __shfl(wval, w * 8 + 6) * x6;
    acc += __shfl(wval, w * 8 + 7) * x7;
    red[w][lane] = acc;
  }
  __syncthreads();

  // ---- phase 4: redundant cross-wave reduce; wave w stores rows w*8..w*8+7,
  // 1 KB contiguous per instruction, plain stores (L3 write absorption) ----
  f4 uv = red[0][lane];
  #pragma unroll
  for (int q = 1; q < 8; ++q) uv += red[q][lane];

  f4* ob4 = reinterpret_cast<f4*>(out) + (size_t)b * 4096;
  const f4 zero = {0.f, 0.f, 0.f, 0.f};
  #pragma unroll
  for (int j = 0; j < 8; ++j) {
    int c = w * 8 + j;                           // wave-uniform row
    ob4[c * 64 + lane] = mc[j] ? uv : zero;
  }
}

extern "C" void kernel_launch(void* const* d_in, const int* in_sizes, int n_in,
                              void* d_out, int out_size, void* d_ws, size_t ws_size,
                              hipStream_t stream) {
  (void)in_sizes; (void)n_in; (void)out_size;
  // inputs: 0 cand [B,C,D] (UNUSED — softmax shift-invariance kills the
  // candidate term), 1 hist [B,H,D], 2 mask_cand, 3 mask_hist,
  // 4 W1 [HID,2D], 5 b1 (unused), 6 W2 [1,HID], 7 b2 (unused)
  const float* hist = (const float*)d_in[1];
  const void*  mask_cand = d_in[2];
  const void*  mask_hist = d_in[3];
  const float* W1 = (const float*)d_in[4];
  const float* W2 = (const float*)d_in[6];
  float* ws = (float*)d_ws;
  float* out = (float*)d_out;

  if (ws_size >= (size_t)(WS_PART_OFF + 64 * ND) * sizeof(float)) {
    precompute_p1<<<64, 256, 0, stream>>>(W1, W2, ws);
    precompute_p2<<<1, 256, 0, stream>>>(
        (const unsigned int*)mask_cand, (const unsigned int*)mask_hist, ws);
  } else {
    precompute_fallback<<<1, 1024, 0, stream>>>(
        W1, W2, (const unsigned int*)mask_cand, (const unsigned int*)mask_hist, ws);
  }
  fused_kernel<<<NB, 512, 0, stream>>>(hist, mask_cand, mask_hist, ws, out);
}

// Round 9
// 40.338 us; speedup vs baseline: 1.2448x; 1.0774x over previous
//
#include <hip/hip_runtime.h>
#include <math.h>

#define NB 1024
#define NC 64
#define NH 64
#define ND 256
#define NHID 256

typedef float f4 __attribute__((ext_vector_type(4)));

// ws layout (floats): [0..255] = v_h, [256] = mask mode (int),
// [1024 .. 1024+64*256) = P1 partials (needs ws >= 69,632 B)
#define WS_PART_OFF 1024

// mask storage modes: 0 = int32, 1 = byte (bool), 2 = float32
__device__ __forceinline__ bool read_mask(const void* m, int idx, int mode) {
  if (mode == 2) return ((const float*)m)[idx] != 0.0f;
  if (mode == 1) return ((const unsigned char*)m)[idx] != 0;
  return ((const int*)m)[idx] != 0;
}

__device__ __forceinline__ void detect_mode(const unsigned int* mask_cand,
                                            const unsigned int* mask_hist,
                                            int* dst) {
  int sawf = 0; unsigned int big = 0;
  for (int i = 0; i < 32; ++i) {
    unsigned int a = mask_hist[i], b = mask_cand[i];
    if (a == 0x3f800000u || b == 0x3f800000u) sawf = 1;
    if ((a > 1u && a != 0x3f800000u) || (b > 1u && b != 0x3f800000u)) big = 1;
  }
  *dst = sawf ? 2 : (big ? 1 : 0);
}

__device__ __forceinline__ float dot4(f4 a, f4 b) {
  return fmaf(a.x, b.x, fmaf(a.y, b.y, fmaf(a.z, b.z, a.w * b.w)));
}

#define BFLY(p) { p += __shfl_xor(p, 32); p += __shfl_xor(p, 16); p += __shfl_xor(p, 8); \
                  p += __shfl_xor(p, 4);  p += __shfl_xor(p, 2);  p += __shfl_xor(p, 1); }

// ---- P1: 64 blocks x 256 threads: partial v_h over 4 j-rows each ----
__global__ __launch_bounds__(256) void precompute_p1(
    const float* __restrict__ W1, const float* __restrict__ W2,
    float* __restrict__ ws)
{
  const int g = blockIdx.x;
  const int d = threadIdx.x;
  float acc = 0.f;
  #pragma unroll
  for (int jj = 0; jj < 4; ++jj) {
    int j = g * 4 + jj;
    acc = fmaf(W1[(size_t)j * (2 * ND) + ND + d], W2[j], acc);
  }
  ws[WS_PART_OFF + g * ND + d] = acc;
}

// ---- P2: 1 block x 256 threads: reduce partials, detect mask mode ----
__global__ __launch_bounds__(256) void precompute_p2(
    const unsigned int* __restrict__ mask_cand,
    const unsigned int* __restrict__ mask_hist,
    float* __restrict__ ws)
{
  const int d = threadIdx.x;
  float acc = 0.f;
  #pragma unroll 8
  for (int g = 0; g < 64; ++g) acc += ws[WS_PART_OFF + g * ND + d];
  ws[d] = acc;
  if (d == 0) detect_mode(mask_cand, mask_hist, (int*)ws + ND);
}

// ---- fallback single-block precompute (small ws) ----
__global__ __launch_bounds__(1024) void precompute_fallback(
    const float* __restrict__ W1, const float* __restrict__ W2,
    const unsigned int* __restrict__ mask_cand,
    const unsigned int* __restrict__ mask_hist,
    float* __restrict__ ws)
{
  __shared__ float w2_lds[NHID];
  __shared__ float partial[4][ND];
  int t = threadIdx.x;
  if (t < NHID) w2_lds[t] = W2[t];
  __syncthreads();
  int d = t & (ND - 1);
  int g = t >> 8;
  float acc = 0.f;
  #pragma unroll 8
  for (int j = g * 64; j < g * 64 + 64; ++j)
    acc = fmaf(W1[(size_t)j * (2 * ND) + ND + d], w2_lds[j], acc);
  partial[g][d] = acc;
  __syncthreads();
  if (t < ND)
    ws[t] = partial[0][t] + partial[1][t] + partial[2][t] + partial[3][t];
  if (t == 0) detect_mode(mask_cand, mask_hist, (int*)ws + ND);
}

// ---- main: 512 blocks x 512 threads; block handles batches b0 = blockIdx
// and b1 = blockIdx + 512, software-pipelined: batch-1 loads issue BEFORE
// batch-0 stores, so the read stream of one overlaps the write stream of the
// other. Double-buffered LDS -> 2 barriers per batch. Wave w owns rows
// w*8..w*8+7 in registers; every load/store instr = 64 x 16 B = 1 KB. ----
__global__ __launch_bounds__(512, 4) void fused2_kernel(
    const float* __restrict__ hist,
    const void* __restrict__ mask_cand_v,
    const void* __restrict__ mask_hist_v,
    const float* __restrict__ ws,
    float* __restrict__ out)
{
  const int b0 = blockIdx.x, b1 = blockIdx.x + 512;
  const int t = threadIdx.x, lane = t & 63, w = t >> 6;
  __shared__ float s_lds[2][NH];
  __shared__ f4 red[2][8][64];                   // 16 KB

  const int mode = ((const int*)ws)[ND];
  const f4 vh = reinterpret_cast<const f4*>(ws)[lane];   // 1 KB, L1-hot
  const f4* h0 = reinterpret_cast<const f4*>(hist) + (size_t)b0 * 4096;
  const f4* h1 = reinterpret_cast<const f4*>(hist) + (size_t)b1 * 4096;
  const f4 zero = {0.f, 0.f, 0.f, 0.f};

  // ================= batch 0: load + scores =================
  f4 x0 = h0[(w * 8 + 0) * 64 + lane], x1 = h0[(w * 8 + 1) * 64 + lane];
  f4 x2 = h0[(w * 8 + 2) * 64 + lane], x3 = h0[(w * 8 + 3) * 64 + lane];
  f4 x4 = h0[(w * 8 + 4) * 64 + lane], x5 = h0[(w * 8 + 5) * 64 + lane];
  f4 x6 = h0[(w * 8 + 6) * 64 + lane], x7 = h0[(w * 8 + 7) * 64 + lane];

  float p0 = dot4(x0, vh), p1 = dot4(x1, vh), p2 = dot4(x2, vh), p3 = dot4(x3, vh);
  float p4 = dot4(x4, vh), p5 = dot4(x5, vh), p6 = dot4(x6, vh), p7 = dot4(x7, vh);
  BFLY(p0) BFLY(p1) BFLY(p2) BFLY(p3) BFLY(p4) BFLY(p5) BFLY(p6) BFLY(p7)
  if (lane < 8) {
    float v = p0;
    if (lane == 1) v = p1;  if (lane == 2) v = p2;  if (lane == 3) v = p3;
    if (lane == 4) v = p4;  if (lane == 5) v = p5;  if (lane == 6) v = p6;
    if (lane == 7) v = p7;
    int h = w * 8 + lane;
    s_lds[0][h] = read_mask(mask_hist_v, b0 * NH + h, mode) ? v : -3.0e38f;
  }
  __syncthreads();

  // softmax (redundant per wave)
  float wval0;
  {
    float s = s_lds[0][lane];
    float m = s;
    m = fmaxf(m, __shfl_xor(m, 32)); m = fmaxf(m, __shfl_xor(m, 16));
    m = fmaxf(m, __shfl_xor(m, 8));  m = fmaxf(m, __shfl_xor(m, 4));
    m = fmaxf(m, __shfl_xor(m, 2));  m = fmaxf(m, __shfl_xor(m, 1));
    float e = expf(s - m);
    float sum = e; BFLY(sum)
    wval0 = e / sum;
  }

  // weighted partial from registers (xs die here)
  {
    f4 acc = __shfl(wval0, w * 8 + 0) * x0;
    acc += __shfl(wval0, w * 8 + 1) * x1;
    acc += __shfl(wval0, w * 8 + 2) * x2;
    acc += __shfl(wval0, w * 8 + 3) * x3;
    acc += __shfl(wval0, w * 8 + 4) * x4;
    acc += __shfl(wval0, w * 8 + 5) * x5;
    acc += __shfl(wval0, w * 8 + 6) * x6;
    acc += __shfl(wval0, w * 8 + 7) * x7;
    red[0][w][lane] = acc;
  }

  // ---- issue batch-1 loads NOW (xs registers are dead; overlaps the
  // barrier + reduce + store phase of batch 0) ----
  f4 y0 = h1[(w * 8 + 0) * 64 + lane], y1 = h1[(w * 8 + 1) * 64 + lane];
  f4 y2 = h1[(w * 8 + 2) * 64 + lane], y3 = h1[(w * 8 + 3) * 64 + lane];
  f4 y4 = h1[(w * 8 + 4) * 64 + lane], y5 = h1[(w * 8 + 5) * 64 + lane];
  f4 y6 = h1[(w * 8 + 6) * 64 + lane], y7 = h1[(w * 8 + 7) * 64 + lane];

  __syncthreads();

  // reduce + store batch 0 (write stream overlaps batch-1 read stream)
  {
    f4 uv = red[0][0][lane];
    #pragma unroll
    for (int q = 1; q < 8; ++q) uv += red[0][q][lane];
    f4* ob4 = reinterpret_cast<f4*>(out) + (size_t)b0 * 4096;
    #pragma unroll
    for (int j = 0; j < 8; ++j) {
      int c = w * 8 + j;
      bool mc = read_mask(mask_cand_v, b0 * NC + c, mode);
      ob4[c * 64 + lane] = mc ? uv : zero;
    }
  }

  // ================= batch 1: scores (ys already in flight) =================
  float q0 = dot4(y0, vh), q1 = dot4(y1, vh), q2 = dot4(y2, vh), q3 = dot4(y3, vh);
  float q4 = dot4(y4, vh), q5 = dot4(y5, vh), q6 = dot4(y6, vh), q7 = dot4(y7, vh);
  BFLY(q0) BFLY(q1) BFLY(q2) BFLY(q3) BFLY(q4) BFLY(q5) BFLY(q6) BFLY(q7)
  if (lane < 8) {
    float v = q0;
    if (lane == 1) v = q1;  if (lane == 2) v = q2;  if (lane == 3) v = q3;
    if (lane == 4) v = q4;  if (lane == 5) v = q5;  if (lane == 6) v = q6;
    if (lane == 7) v = q7;
    int h = w * 8 + lane;
    s_lds[1][h] = read_mask(mask_hist_v, b1 * NH + h, mode) ? v : -3.0e38f;
  }
  __syncthreads();

  float wval1;
  {
    float s = s_lds[1][lane];
    float m = s;
    m = fmaxf(m, __shfl_xor(m, 32)); m = fmaxf(m, __shfl_xor(m, 16));
    m = fmaxf(m, __shfl_xor(m, 8));  m = fmaxf(m, __shfl_xor(m, 4));
    m = fmaxf(m, __shfl_xor(m, 2));  m = fmaxf(m, __shfl_xor(m, 1));
    float e = expf(s - m);
    float sum = e; BFLY(sum)
    wval1 = e / sum;
  }

  {
    f4 acc = __shfl(wval1, w * 8 + 0) * y0;
    acc += __shfl(wval1, w * 8 + 1) * y1;
    acc += __shfl(wval1, w * 8 + 2) * y2;
    acc += __shfl(wval1, w * 8 + 3) * y3;
    acc += __shfl(wval1, w * 8 + 4) * y4;
    acc += __shfl(wval1, w * 8 + 5) * y5;
    acc += __shfl(wval1, w * 8 + 6) * y6;
    acc += __shfl(wval1, w * 8 + 7) * y7;
    red[1][w][lane] = acc;
  }
  __syncthreads();

  {
    f4 uv = red[1][0][lane];
    #pragma unroll
    for (int q = 1; q < 8; ++q) uv += red[1][q][lane];
    f4* ob4 = reinterpret_cast<f4*>(out) + (size_t)b1 * 4096;
    #pragma unroll
    for (int j = 0; j < 8; ++j) {
      int c = w * 8 + j;
      bool mc = read_mask(mask_cand_v, b1 * NC + c, mode);
      ob4[c * 64 + lane] = mc ? uv : zero;
    }
  }
}

extern "C" void kernel_launch(void* const* d_in, const int* in_sizes, int n_in,
                              void* d_out, int out_size, void* d_ws, size_t ws_size,
                              hipStream_t stream) {
  (void)in_sizes; (void)n_in; (void)out_size;
  // inputs: 0 cand [B,C,D] (UNUSED — softmax shift-invariance kills the
  // candidate term), 1 hist [B,H,D], 2 mask_cand, 3 mask_hist,
  // 4 W1 [HID,2D], 5 b1 (unused), 6 W2 [1,HID], 7 b2 (unused)
  const float* hist = (const float*)d_in[1];
  const void*  mask_cand = d_in[2];
  const void*  mask_hist = d_in[3];
  const float* W1 = (const float*)d_in[4];
  const float* W2 = (const float*)d_in[6];
  float* ws = (float*)d_ws;
  float* out = (float*)d_out;

  if (ws_size >= (size_t)(WS_PART_OFF + 64 * ND) * sizeof(float)) {
    precompute_p1<<<64, 256, 0, stream>>>(W1, W2, ws);
    precompute_p2<<<1, 256, 0, stream>>>(
        (const unsigned int*)mask_cand, (const unsigned int*)mask_hist, ws);
  } else {
    precompute_fallback<<<1, 1024, 0, stream>>>(
        W1, W2, (const unsigned int*)mask_cand, (const unsigned int*)mask_hist, ws);
  }
  fused2_kernel<<<NB / 2, 512, 0, stream>>>(hist, mask_cand, mask_hist, ws, out);
}

// Round 10
// 39.921 us; speedup vs baseline: 1.2578x; 1.0104x over previous
//
#include <hip/hip_runtime.h>
#include <math.h>

#define NB 1024
#define NC 64
#define NH 64
#define ND 256
#define NHID 256

typedef float f4 __attribute__((ext_vector_type(4)));

// ws layout (floats): [0..255] = v_h, [256] = mask mode (int),
// [1024 .. 1024+64*256) = P1 partials (needs ws >= 69,632 B)
#define WS_PART_OFF 1024

// Raw barrier with LDS-only drain: DS ops (shared mem, shfl) complete, but
// global loads/stores stay IN FLIGHT across the barrier (unlike
// __syncthreads(), which drains vmcnt(0) and kills read/write overlap).
#define BAR_LGKM() asm volatile("s_waitcnt lgkmcnt(0)\n\ts_barrier" ::: "memory")

// mask storage modes: 0 = int32, 1 = byte (bool), 2 = float32
__device__ __forceinline__ bool read_mask(const void* m, int idx, int mode) {
  if (mode == 2) return ((const float*)m)[idx] != 0.0f;
  if (mode == 1) return ((const unsigned char*)m)[idx] != 0;
  return ((const int*)m)[idx] != 0;
}

__device__ __forceinline__ void detect_mode(const unsigned int* mask_cand,
                                            const unsigned int* mask_hist,
                                            int* dst) {
  int sawf = 0; unsigned int big = 0;
  for (int i = 0; i < 32; ++i) {
    unsigned int a = mask_hist[i], b = mask_cand[i];
    if (a == 0x3f800000u || b == 0x3f800000u) sawf = 1;
    if ((a > 1u && a != 0x3f800000u) || (b > 1u && b != 0x3f800000u)) big = 1;
  }
  *dst = sawf ? 2 : (big ? 1 : 0);
}

__device__ __forceinline__ float dot4(f4 a, f4 b) {
  return fmaf(a.x, b.x, fmaf(a.y, b.y, fmaf(a.z, b.z, a.w * b.w)));
}

#define BFLY(p) { p += __shfl_xor(p, 32); p += __shfl_xor(p, 16); p += __shfl_xor(p, 8); \
                  p += __shfl_xor(p, 4);  p += __shfl_xor(p, 2);  p += __shfl_xor(p, 1); }

// ---- P1: 64 blocks x 256 threads: partial v_h over 4 j-rows each ----
__global__ __launch_bounds__(256) void precompute_p1(
    const float* __restrict__ W1, const float* __restrict__ W2,
    float* __restrict__ ws)
{
  const int g = blockIdx.x;
  const int d = threadIdx.x;
  float acc = 0.f;
  #pragma unroll
  for (int jj = 0; jj < 4; ++jj) {
    int j = g * 4 + jj;
    acc = fmaf(W1[(size_t)j * (2 * ND) + ND + d], W2[j], acc);
  }
  ws[WS_PART_OFF + g * ND + d] = acc;
}

// ---- P2: 1 block x 256 threads: reduce partials, detect mask mode ----
__global__ __launch_bounds__(256) void precompute_p2(
    const unsigned int* __restrict__ mask_cand,
    const unsigned int* __restrict__ mask_hist,
    float* __restrict__ ws)
{
  const int d = threadIdx.x;
  float acc = 0.f;
  #pragma unroll 8
  for (int g = 0; g < 64; ++g) acc += ws[WS_PART_OFF + g * ND + d];
  ws[d] = acc;
  if (d == 0) detect_mode(mask_cand, mask_hist, (int*)ws + ND);
}

// ---- fallback single-block precompute (small ws) ----
__global__ __launch_bounds__(1024) void precompute_fallback(
    const float* __restrict__ W1, const float* __restrict__ W2,
    const unsigned int* __restrict__ mask_cand,
    const unsigned int* __restrict__ mask_hist,
    float* __restrict__ ws)
{
  __shared__ float w2_lds[NHID];
  __shared__ float partial[4][ND];
  int t = threadIdx.x;
  if (t < NHID) w2_lds[t] = W2[t];
  __syncthreads();
  int d = t & (ND - 1);
  int g = t >> 8;
  float acc = 0.f;
  #pragma unroll 8
  for (int j = g * 64; j < g * 64 + 64; ++j)
    acc = fmaf(W1[(size_t)j * (2 * ND) + ND + d], w2_lds[j], acc);
  partial[g][d] = acc;
  __syncthreads();
  if (t < ND)
    ws[t] = partial[0][t] + partial[1][t] + partial[2][t] + partial[3][t];
  if (t == 0) detect_mode(mask_cand, mask_hist, (int*)ws + ND);
}

// ---- main: 512 blocks x 512 threads; block handles b0 = blockIdx and
// b1 = blockIdx + 512. ALL 16 row-loads (both batches) issue in the
// prologue; barriers are lgkm-only so global traffic streams across them.
// Wave w owns rows w*8..w*8+7 in registers; every global load/store
// instruction is 64 lanes x 16 B = 1 KB contiguous. ----
__global__ __launch_bounds__(512, 4) void fused2_kernel(
    const float* __restrict__ hist,
    const void* __restrict__ mask_cand_v,
    const void* __restrict__ mask_hist_v,
    const float* __restrict__ ws,
    float* __restrict__ out)
{
  const int b0 = blockIdx.x, b1 = blockIdx.x + 512;
  const int t = threadIdx.x, lane = t & 63, w = t >> 6;
  __shared__ float s_lds[2][NH];
  __shared__ f4 red[2][8][64];                   // 16 KB

  const int mode = ((const int*)ws)[ND];
  const f4 vh = reinterpret_cast<const f4*>(ws)[lane];   // 1 KB, L1-hot
  const f4* h0 = reinterpret_cast<const f4*>(hist) + (size_t)b0 * 4096;
  const f4* h1 = reinterpret_cast<const f4*>(hist) + (size_t)b1 * 4096;
  const f4 zero = {0.f, 0.f, 0.f, 0.f};

  // ---- prologue: 16 independent 1 KB-contiguous loads, all in flight ----
  f4 x0 = h0[(w * 8 + 0) * 64 + lane], x1 = h0[(w * 8 + 1) * 64 + lane];
  f4 x2 = h0[(w * 8 + 2) * 64 + lane], x3 = h0[(w * 8 + 3) * 64 + lane];
  f4 x4 = h0[(w * 8 + 4) * 64 + lane], x5 = h0[(w * 8 + 5) * 64 + lane];
  f4 x6 = h0[(w * 8 + 6) * 64 + lane], x7 = h0[(w * 8 + 7) * 64 + lane];
  f4 y0 = h1[(w * 8 + 0) * 64 + lane], y1 = h1[(w * 8 + 1) * 64 + lane];
  f4 y2 = h1[(w * 8 + 2) * 64 + lane], y3 = h1[(w * 8 + 3) * 64 + lane];
  f4 y4 = h1[(w * 8 + 4) * 64 + lane], y5 = h1[(w * 8 + 5) * 64 + lane];
  f4 y6 = h1[(w * 8 + 6) * 64 + lane], y7 = h1[(w * 8 + 7) * 64 + lane];

  // ================= batch 0 =================
  {
    float p0 = dot4(x0, vh), p1 = dot4(x1, vh), p2 = dot4(x2, vh), p3 = dot4(x3, vh);
    float p4 = dot4(x4, vh), p5 = dot4(x5, vh), p6 = dot4(x6, vh), p7 = dot4(x7, vh);
    BFLY(p0) BFLY(p1) BFLY(p2) BFLY(p3) BFLY(p4) BFLY(p5) BFLY(p6) BFLY(p7)
    if (lane < 8) {
      float v = p0;
      if (lane == 1) v = p1;  if (lane == 2) v = p2;  if (lane == 3) v = p3;
      if (lane == 4) v = p4;  if (lane == 5) v = p5;  if (lane == 6) v = p6;
      if (lane == 7) v = p7;
      int h = w * 8 + lane;
      s_lds[0][h] = read_mask(mask_hist_v, b0 * NH + h, mode) ? v : -3.0e38f;
    }
  }
  BAR_LGKM();                       // y-loads remain in flight

  float wval0;
  {
    float s = s_lds[0][lane];
    float m = s;
    m = fmaxf(m, __shfl_xor(m, 32)); m = fmaxf(m, __shfl_xor(m, 16));
    m = fmaxf(m, __shfl_xor(m, 8));  m = fmaxf(m, __shfl_xor(m, 4));
    m = fmaxf(m, __shfl_xor(m, 2));  m = fmaxf(m, __shfl_xor(m, 1));
    float e = expf(s - m);
    float sum = e; BFLY(sum)
    wval0 = e / sum;
  }
  {
    f4 acc = __shfl(wval0, w * 8 + 0) * x0;
    acc += __shfl(wval0, w * 8 + 1) * x1;
    acc += __shfl(wval0, w * 8 + 2) * x2;
    acc += __shfl(wval0, w * 8 + 3) * x3;
    acc += __shfl(wval0, w * 8 + 4) * x4;
    acc += __shfl(wval0, w * 8 + 5) * x5;
    acc += __shfl(wval0, w * 8 + 6) * x6;
    acc += __shfl(wval0, w * 8 + 7) * x7;
    red[0][w][lane] = acc;
  }
  BAR_LGKM();

  {
    f4 uv = red[0][0][lane];
    #pragma unroll
    for (int q = 1; q < 8; ++q) uv += red[0][q][lane];
    f4* ob4 = reinterpret_cast<f4*>(out) + (size_t)b0 * 4096;
    #pragma unroll
    for (int j = 0; j < 8; ++j) {
      int c = w * 8 + j;
      bool mc = read_mask(mask_cand_v, b0 * NC + c, mode);
      ob4[c * 64 + lane] = mc ? uv : zero;      // stores overlap batch-1 compute
    }
  }

  // ================= batch 1 =================
  {
    float p0 = dot4(y0, vh), p1 = dot4(y1, vh), p2 = dot4(y2, vh), p3 = dot4(y3, vh);
    float p4 = dot4(y4, vh), p5 = dot4(y5, vh), p6 = dot4(y6, vh), p7 = dot4(y7, vh);
    BFLY(p0) BFLY(p1) BFLY(p2) BFLY(p3) BFLY(p4) BFLY(p5) BFLY(p6) BFLY(p7)
    if (lane < 8) {
      float v = p0;
      if (lane == 1) v = p1;  if (lane == 2) v = p2;  if (lane == 3) v = p3;
      if (lane == 4) v = p4;  if (lane == 5) v = p5;  if (lane == 6) v = p6;
      if (lane == 7) v = p7;
      int h = w * 8 + lane;
      s_lds[1][h] = read_mask(mask_hist_v, b1 * NH + h, mode) ? v : -3.0e38f;
    }
  }
  BAR_LGKM();

  float wval1;
  {
    float s = s_lds[1][lane];
    float m = s;
    m = fmaxf(m, __shfl_xor(m, 32)); m = fmaxf(m, __shfl_xor(m, 16));
    m = fmaxf(m, __shfl_xor(m, 8));  m = fmaxf(m, __shfl_xor(m, 4));
    m = fmaxf(m, __shfl_xor(m, 2));  m = fmaxf(m, __shfl_xor(m, 1));
    float e = expf(s - m);
    float sum = e; BFLY(sum)
    wval1 = e / sum;
  }
  {
    f4 acc = __shfl(wval1, w * 8 + 0) * y0;
    acc += __shfl(wval1, w * 8 + 1) * y1;
    acc += __shfl(wval1, w * 8 + 2) * y2;
    acc += __shfl(wval1, w * 8 + 3) * y3;
    acc += __shfl(wval1, w * 8 + 4) * y4;
    acc += __shfl(wval1, w * 8 + 5) * y5;
    acc += __shfl(wval1, w * 8 + 6) * y6;
    acc += __shfl(wval1, w * 8 + 7) * y7;
    red[1][w][lane] = acc;
  }
  BAR_LGKM();

  {
    f4 uv = red[1][0][lane];
    #pragma unroll
    for (int q = 1; q < 8; ++q) uv += red[1][q][lane];
    f4* ob4 = reinterpret_cast<f4*>(out) + (size_t)b1 * 4096;
    #pragma unroll
    for (int j = 0; j < 8; ++j) {
      int c = w * 8 + j;
      bool mc = read_mask(mask_cand_v, b1 * NC + c, mode);
      ob4[c * 64 + lane] = mc ? uv : zero;
    }
  }
}

extern "C" void kernel_launch(void* const* d_in, const int* in_sizes, int n_in,
                              void* d_out, int out_size, void* d_ws, size_t ws_size,
                              hipStream_t stream) {
  (void)in_sizes; (void)n_in; (void)out_size;
  // inputs: 0 cand [B,C,D] (UNUSED — softmax shift-invariance kills the
  // candidate term), 1 hist [B,H,D], 2 mask_cand, 3 mask_hist,
  // 4 W1 [HID,2D], 5 b1 (unused), 6 W2 [1,HID], 7 b2 (unused)
  const float* hist = (const float*)d_in[1];
  const void*  mask_cand = d_in[2];
  const void*  mask_hist = d_in[3];
  const float* W1 = (const float*)d_in[4];
  const float* W2 = (const float*)d_in[6];
  float* ws = (float*)d_ws;
  float* out = (float*)d_out;

  if (ws_size >= (size_t)(WS_PART_OFF + 64 * ND) * sizeof(float)) {
    precompute_p1<<<64, 256, 0, stream>>>(W1, W2, ws);
    precompute_p2<<<1, 256, 0, stream>>>(
        (const unsigned int*)mask_cand, (const unsigned int*)mask_hist, ws);
  } else {
    precompute_fallback<<<1, 1024, 0, stream>>>(
        W1, W2, (const unsigned int*)mask_cand, (const unsigned int*)mask_hist, ws);
  }
  fused2_kernel<<<NB / 2, 512, 0, stream>>>(hist, mask_cand, mask_hist, ws, out);
}